// Round 8
// baseline (97.926 us; speedup 1.0000x reference)
//
#include <hip/hip_runtime.h>
#include <hip/hip_bf16.h>

#define BB 8
#define SS 8192
#define FF 512
#define EE 128
#define CC 1000

typedef __bf16 bf16x8 __attribute__((ext_vector_type(8)));
typedef float  f32x4  __attribute__((ext_vector_type(4)));

// ---------------- K0: transpose-convert W (F,E) f32 -> Wt (E,F) bf16 ----------------
__global__ void k0_wt(const float* __restrict__ W, __bf16* __restrict__ Wt) {
    int idx = blockIdx.x * 256 + threadIdx.x;   // 65536 = F*E
    int e = idx & (EE - 1);
    int f = idx >> 7;
    Wt[e * FF + f] = (__bf16)W[f * EE + e];
}

// ---------------- FUSED: barrier-free diff-GEMM (full Wt in LDS) -> exp -> wsum ----------
// grid = 512 blocks (b = bid>>6, chunk = bid&63 of 128 rows), 512 threads (8 waves).
// Wt (128x512 bf16 = 128 KB) is staged into LDS ONCE; the K-loop then has ZERO barriers
// and ZERO LDS writes: each wave independently streams its 16-row sx strip through a
// 4-slot register pipeline (3-deep prefetch), does diff+cvt in regs, MFMAs vs LDS Wt.
__global__ __launch_bounds__(512, 2) void k_fused(
    const float* __restrict__ x,          // (B,F)
    const float* __restrict__ sx,         // (B,S,F)
    const __bf16* __restrict__ Wt,        // (E,F) bf16
    const float* __restrict__ y,          // (B,S,C)
    float* __restrict__ pout,             // (B,64,C) partial numerators
    float* __restrict__ pden)             // (B,64)   partial denominators
{
    __shared__ __bf16 lB[16][4][128][8];  // 128 KB: the ENTIRE Wt, layout [t][kgrp][e][8]
    __shared__ float  wv[128];

    const int tid   = threadIdx.x;
    const int b     = blockIdx.x >> 6;
    const int chunk = blockIdx.x & 63;
    const int srow0 = chunk << 7;

    const int lane = tid & 63;
    const int w    = tid >> 6;        // wave 0..7 -> rows w*16 .. w*16+15
    const int lg   = lane >> 4;       // k-subgroup 0..3 (8 k-elements)
    const int lr   = lane & 15;

    // ---- stage the whole Wt into LDS, once (4096 chunks of 32 B, coalesced) ----
    #pragma unroll
    for (int i = 0; i < 8; i++) {
        int c  = tid + i * 512;       // 0..4095
        int e  = c >> 5;
        int r  = c & 31;
        int t  = r >> 1;
        int kh = r & 1;
        const __bf16* p = Wt + (size_t)e * FF + t * 32 + kh * 16;
        *(bf16x8*)&lB[t][kh*2+0][e][0] = *(const bf16x8*)(p);
        *(bf16x8*)&lB[t][kh*2+1][e][0] = *(const bf16x8*)(p + 8);
    }
    __syncthreads();   // the ONLY barrier before the epilogue

    const float* Ap = sx + ((size_t)b * SS + srow0 + w * 16 + lr) * FF + lg * 8;
    const float* xp = x + b * FF + lg * 8;

    f32x4 acc[8];
    #pragma unroll
    for (int n = 0; n < 8; n++) { f32x4 z = {0.f, 0.f, 0.f, 0.f}; acc[n] = z; }

    // 4-slot register pipeline; fully unrolled loop -> all indices compile-time
    float4 sS[4][2], xS[4][2];

    auto LOAD = [&](int t, int slot) {
        sS[slot][0] = *(const float4*)(Ap + t * 32);
        sS[slot][1] = *(const float4*)(Ap + t * 32 + 4);
        xS[slot][0] = *(const float4*)(xp + t * 32);
        xS[slot][1] = *(const float4*)(xp + t * 32 + 4);
    };
    auto COMPUTE = [&](int t, int slot) {
        __bf16 d[8];
        #pragma unroll
        for (int i = 0; i < 2; i++) {
            d[4*i+0] = (__bf16)(xS[slot][i].x - sS[slot][i].x);
            d[4*i+1] = (__bf16)(xS[slot][i].y - sS[slot][i].y);
            d[4*i+2] = (__bf16)(xS[slot][i].z - sS[slot][i].z);
            d[4*i+3] = (__bf16)(xS[slot][i].w - sS[slot][i].w);
        }
        bf16x8 af = *(bf16x8*)d;
        #pragma unroll
        for (int n = 0; n < 8; n++) {
            bf16x8 bfr = *(const bf16x8*)&lB[t][lg][n * 16 + lr][0];
            acc[n] = __builtin_amdgcn_mfma_f32_16x16x32_bf16(af, bfr, acc[n], 0, 0, 0);
        }
    };

    // ---- Phase 1: K-loop, barrier-free, 3-deep prefetch ----
    LOAD(0, 0); LOAD(1, 1); LOAD(2, 2);
    #pragma unroll
    for (int t = 0; t < 16; t++) {
        COMPUTE(t, t & 3);
        if (t + 3 < 16) LOAD(t + 3, (t + 3) & 3);
    }

    // ---- Epilogue: per-row ||.||^2 -> wv[row] = exp(-sqrt(.)) ----
    // Wave owns full E for its 16 rows: D row = lg*4 + j, col = n*16 + lr.
    float rp[4];
    #pragma unroll
    for (int j = 0; j < 4; j++) {
        float s = 0.f;
        #pragma unroll
        for (int n = 0; n < 8; n++) { float v = acc[n][j]; s += v * v; }
        rp[j] = s;
    }
    #pragma unroll
    for (int mask = 1; mask < 16; mask <<= 1)
        #pragma unroll
        for (int j = 0; j < 4; j++)
            rp[j] += __shfl_xor(rp[j], mask);

    if (lr == 0) {
        #pragma unroll
        for (int j = 0; j < 4; j++)
            wv[w * 16 + lg * 4 + j] = expf(-sqrtf(rp[j]));
    }
    __syncthreads();

    // partial denominator: wave 0 reduces wv[0..127]
    if (w == 0) {
        float dsum = wv[lane] + wv[lane + 64];
        #pragma unroll
        for (int mask = 1; mask < 64; mask <<= 1)
            dsum += __shfl_xor(dsum, mask);
        if (lane == 0) pden[b * 64 + chunk] = dsum;
    }

    // ---- Phase 2: weighted partial sum over support_y (128 rows x 1000 classes) ----
    if (tid < 500) {
        float a0 = 0.f, a1 = 0.f;
        const float* base = y + ((size_t)b * SS + srow0) * CC + tid * 2;
        #pragma unroll 8
        for (int r = 0; r < 128; r++) {
            float2 v = *(const float2*)(base + (size_t)r * CC);
            float wgt = wv[r];
            a0 += wgt * v.x; a1 += wgt * v.y;
        }
        float2 res = {a0, a1};
        *(float2*)(pout + ((size_t)(b * 64 + chunk)) * CC + tid * 2) = res;
    }
}

// ---------------- K4: final reduction over 64 chunks ----------------
__global__ void k4_final(const float* __restrict__ pout, const float* __restrict__ pden,
                         float* __restrict__ out) {
    int idx = blockIdx.x * 256 + threadIdx.x;
    if (idx >= BB * CC) return;
    int b = idx / CC, c = idx % CC;
    float den = 0.f;
    #pragma unroll 8
    for (int k = 0; k < 64; k++) den += pden[b * 64 + k];
    float num = 0.f;
    #pragma unroll 8
    for (int k = 0; k < 64; k++) num += pout[((size_t)(b * 64 + k)) * CC + c];
    out[idx] = num / den;
}

extern "C" void kernel_launch(void* const* d_in, const int* in_sizes, int n_in,
                              void* d_out, int out_size, void* d_ws, size_t ws_size,
                              hipStream_t stream) {
    const float* x  = (const float*)d_in[0];
    const float* sx = (const float*)d_in[1];
    const float* sy = (const float*)d_in[2];
    const float* W  = (const float*)d_in[3];

    char* ws = (char*)d_ws;
    __bf16* Wt   = (__bf16*)(ws);                        // 131072 B
    float*  pout = (float*)(ws + 131072);                // 2048000 B
    float*  pden = (float*)(ws + 131072 + 2048000);      // 2048 B

    k0_wt<<<256, 256, 0, stream>>>(W, Wt);
    k_fused<<<512, 512, 0, stream>>>(x, sx, Wt, sy, pout, pden);
    k4_final<<<32, 256, 0, stream>>>(pout, pden, (float*)d_out);
}

// Round 10
// 97.191 us; speedup vs baseline: 1.0076x; 1.0076x over previous
//
#include <hip/hip_runtime.h>
#include <hip/hip_bf16.h>

#define BB 8
#define SS 8192
#define FF 512
#define EE 128
#define CC 1000

typedef __bf16 bf16x8 __attribute__((ext_vector_type(8)));
typedef float  f32x4  __attribute__((ext_vector_type(4)));

// Relaxed barrier: LDS visibility only, no vmcnt drain (y prefetch survives).
#define BAR_RELAXED() do { \
    asm volatile("s_waitcnt lgkmcnt(0)" ::: "memory"); \
    __builtin_amdgcn_s_barrier(); \
} while (0)

// ---------------- K0: transpose-convert W (F,E) f32 -> Wt (E,F) bf16 ----------------
__global__ void k0_wt(const float* __restrict__ W, __bf16* __restrict__ Wt) {
    int idx = blockIdx.x * 256 + threadIdx.x;   // 65536 = F*E
    int e = idx & (EE - 1);
    int f = idx >> 7;
    Wt[e * FF + f] = (__bf16)W[f * EE + e];
}

// ---------------- FUSED, chunk-paired ----------------
// grid = 256 blocks (b = bid>>5, pair = bid&31 -> chunks c0=2p, c1=2p+1), 256 threads.
// Block: P1(c0) -> [P1(c1) with P2(c0) y-streaming interleaved per K-step] -> P2(c1).
// The interleave mixes y HBM traffic into phase-1's barrier bubbles.
__global__ __launch_bounds__(256) void k_fused(
    const float* __restrict__ x,          // (B,F)
    const float* __restrict__ sx,         // (B,S,F)
    const __bf16* __restrict__ Wt,        // (E,F) bf16
    const float* __restrict__ y,          // (B,S,C)
    float* __restrict__ pout,             // (B,64,C)
    float* __restrict__ pden)             // (B,64)
{
    __shared__ __bf16 lA[2][4][128][8];   // 16 KB diff tile
    __shared__ __bf16 lB[2][4][128][8];   // 16 KB W tile
    __shared__ float  scp[2][128];
    __shared__ float  wv[2][128];

    const int tid  = threadIdx.x;
    const int bid  = blockIdx.x;
    const int b    = bid >> 5;
    const int pair = bid & 31;
    const int c0   = pair * 2;
    const int c1   = pair * 2 + 1;
    const float* Xb0 = sx + ((size_t)b * SS + (c0 << 7)) * FF;
    const float* Xb1 = sx + ((size_t)b * SS + (c1 << 7)) * FF;
    const float* xb  = x + b * FF;

    const int row  = tid >> 1;        // 0..127 (also 'e' for B staging)
    const int kh   = tid & 1;
    const int lane = tid & 63;
    const int w    = tid >> 6;        // wave 0..3
    const int wrow = (w >> 1) * 64;
    const int wcol = (w & 1) * 64;
    const int lg   = lane >> 4;
    const int lr   = lane & 15;

    f32x4 acc[4][4];
    float4 sReg[4], xReg[4];

    auto ZEROACC = [&]() {
        #pragma unroll
        for (int m = 0; m < 4; m++)
            #pragma unroll
            for (int n = 0; n < 4; n++) { f32x4 z = {0.f, 0.f, 0.f, 0.f}; acc[m][n] = z; }
    };
    auto LOADT = [&](const float* Xb, int t) {
        const float* pS = Xb + (size_t)row * FF + t * 32 + kh * 16;
        const float* pX = xb + t * 32 + kh * 16;
        #pragma unroll
        for (int i = 0; i < 4; i++) {
            sReg[i] = *(const float4*)(pS + 4 * i);
            xReg[i] = *(const float4*)(pX + 4 * i);
        }
    };
    auto WRITET = [&](int buf) {
        __bf16 d[16];
        #pragma unroll
        for (int i = 0; i < 4; i++) {
            d[4*i+0] = (__bf16)(xReg[i].x - sReg[i].x);
            d[4*i+1] = (__bf16)(xReg[i].y - sReg[i].y);
            d[4*i+2] = (__bf16)(xReg[i].z - sReg[i].z);
            d[4*i+3] = (__bf16)(xReg[i].w - sReg[i].w);
        }
        *(bf16x8*)&lA[buf][kh*2+0][row][0] = *(bf16x8*)&d[0];
        *(bf16x8*)&lA[buf][kh*2+1][row][0] = *(bf16x8*)&d[8];
    };
    auto STAGEB = [&](int buf, int t) {
        const __bf16* pW = Wt + (size_t)row * FF + t * 32 + kh * 16;  // row == e
        bf16x8 w0 = *(const bf16x8*)(pW);
        bf16x8 w1 = *(const bf16x8*)(pW + 8);
        *(bf16x8*)&lB[buf][kh*2+0][row][0] = w0;
        *(bf16x8*)&lB[buf][kh*2+1][row][0] = w1;
    };
    auto MFMA_STEP = [&](int buf) {
        bf16x8 af[4], bfr[4];
        #pragma unroll
        for (int m = 0; m < 4; m++)
            af[m] = *(const bf16x8*)&lA[buf][lg][wrow + m * 16 + lr][0];
        #pragma unroll
        for (int n = 0; n < 4; n++)
            bfr[n] = *(const bf16x8*)&lB[buf][lg][wcol + n * 16 + lr][0];
        #pragma unroll
        for (int m = 0; m < 4; m++)
            #pragma unroll
            for (int n = 0; n < 4; n++)
                acc[m][n] = __builtin_amdgcn_mfma_f32_16x16x32_bf16(af[m], bfr[n], acc[m][n], 0, 0, 0);
    };
    auto EPILOGUE = [&](int which, int chunk) {
        // C/D layout: col = wcol + n*16 + lr ; row = wrow + m*16 + lg*4 + j
        float rp[4][4];
        #pragma unroll
        for (int m = 0; m < 4; m++)
            #pragma unroll
            for (int j = 0; j < 4; j++) {
                float s = 0.f;
                #pragma unroll
                for (int n = 0; n < 4; n++) { float v = acc[m][n][j]; s += v * v; }
                rp[m][j] = s;
            }
        #pragma unroll
        for (int mask = 1; mask < 16; mask <<= 1)
            #pragma unroll
            for (int m = 0; m < 4; m++)
                #pragma unroll
                for (int j = 0; j < 4; j++)
                    rp[m][j] += __shfl_xor(rp[m][j], mask);
        if (lr == 0) {
            #pragma unroll
            for (int m = 0; m < 4; m++)
                #pragma unroll
                for (int j = 0; j < 4; j++)
                    scp[w & 1][wrow + m * 16 + lg * 4 + j] = rp[m][j];
        }
        __syncthreads();
        if (tid < 128)
            wv[which][tid] = expf(-sqrtf(scp[0][tid] + scp[1][tid]));
        __syncthreads();
        if (w == 0) {
            float d = wv[which][lane] + wv[which][lane + 64];
            #pragma unroll
            for (int mask = 1; mask < 64; mask <<= 1)
                d += __shfl_xor(d, mask);
            if (lane == 0) pden[b * 64 + chunk] = d;
        }
    };

    // ================= P1(c0) — r2-exact =================
    ZEROACC();
    LOADT(Xb0, 0); STAGEB(0, 0); WRITET(0);
    __syncthreads();
    for (int t = 0; t < 16; t++) {
        const int cur = t & 1;
        if (t < 15) { LOADT(Xb0, t + 1); STAGEB(cur ^ 1, t + 1); }
        MFMA_STEP(cur);
        if (t < 15) WRITET(cur ^ 1);
        __syncthreads();
    }
    EPILOGUE(0, c0);

    // ================= interleaved: P1(c1) + P2(c0) =================
    ZEROACC();
    const bool act = (tid < 250);
    const float* yb0 = y + ((size_t)b * SS + (c0 << 7)) * CC + tid * 4;
    const float* yb1 = y + ((size_t)b * SS + (c1 << 7)) * CC + tid * 4;
    float4 yA[8], yB[8];
    float a0 = 0.f, a1 = 0.f, a2 = 0.f, a3 = 0.f;

    LOADT(Xb1, 0); STAGEB(0, 0); WRITET(0);
    if (act) {
        #pragma unroll
        for (int i = 0; i < 8; i++) yA[i] = *(const float4*)(yb0 + (size_t)i * CC);
    }
    __syncthreads();

    #pragma unroll
    for (int t = 0; t < 16; t++) {
        const int cur = t & 1;
        if (t < 15) { LOADT(Xb1, t + 1); STAGEB(cur ^ 1, t + 1); }
        if (t + 1 < 16 && act) {          // issue y group t+1 into set (t+1)&1
            if ((t + 1) & 1) {
                #pragma unroll
                for (int i = 0; i < 8; i++)
                    yB[i] = *(const float4*)(yb0 + (size_t)(8 * (t + 1) + i) * CC);
            } else {
                #pragma unroll
                for (int i = 0; i < 8; i++)
                    yA[i] = *(const float4*)(yb0 + (size_t)(8 * (t + 1) + i) * CC);
            }
        }
        MFMA_STEP(cur);
        if (act) {                        // consume y group t from set t&1
            if (t & 1) {
                #pragma unroll
                for (int i = 0; i < 8; i++) {
                    float wgt = wv[0][8 * t + i];
                    a0 += wgt * yB[i].x; a1 += wgt * yB[i].y;
                    a2 += wgt * yB[i].z; a3 += wgt * yB[i].w;
                }
            } else {
                #pragma unroll
                for (int i = 0; i < 8; i++) {
                    float wgt = wv[0][8 * t + i];
                    a0 += wgt * yA[i].x; a1 += wgt * yA[i].y;
                    a2 += wgt * yA[i].z; a3 += wgt * yA[i].w;
                }
            }
        }
        if (t < 15) WRITET(cur ^ 1);
        BAR_RELAXED();
    }
    if (act) {
        float4 res = {a0, a1, a2, a3};
        *(float4*)(pout + ((size_t)(b * 64 + c0)) * CC + tid * 4) = res;
    }

    EPILOGUE(1, c1);

    // ================= P2(c1) =================
    if (act) {
        float e0 = 0.f, e1 = 0.f, e2 = 0.f, e3 = 0.f;
        #pragma unroll 8
        for (int r = 0; r < 128; r++) {
            float4 v = *(const float4*)(yb1 + (size_t)r * CC);
            float wgt = wv[1][r];
            e0 += wgt * v.x; e1 += wgt * v.y; e2 += wgt * v.z; e3 += wgt * v.w;
        }
        float4 res = {e0, e1, e2, e3};
        *(float4*)(pout + ((size_t)(b * 64 + c1)) * CC + tid * 4) = res;
    }
}

// ---------------- K4: final reduction over 64 chunks ----------------
__global__ void k4_final(const float* __restrict__ pout, const float* __restrict__ pden,
                         float* __restrict__ out) {
    int idx = blockIdx.x * 256 + threadIdx.x;
    if (idx >= BB * CC) return;
    int b = idx / CC, c = idx % CC;
    float den = 0.f;
    #pragma unroll 8
    for (int k = 0; k < 64; k++) den += pden[b * 64 + k];
    float num = 0.f;
    #pragma unroll 8
    for (int k = 0; k < 64; k++) num += pout[((size_t)(b * 64 + k)) * CC + c];
    out[idx] = num / den;
}

extern "C" void kernel_launch(void* const* d_in, const int* in_sizes, int n_in,
                              void* d_out, int out_size, void* d_ws, size_t ws_size,
                              hipStream_t stream) {
    const float* x  = (const float*)d_in[0];
    const float* sx = (const float*)d_in[1];
    const float* sy = (const float*)d_in[2];
    const float* W  = (const float*)d_in[3];

    char* ws = (char*)d_ws;
    __bf16* Wt   = (__bf16*)(ws);                        // 131072 B
    float*  pout = (float*)(ws + 131072);                // 2048000 B
    float*  pden = (float*)(ws + 131072 + 2048000);      // 2048 B

    k0_wt<<<256, 256, 0, stream>>>(W, Wt);
    k_fused<<<256, 256, 0, stream>>>(x, sx, Wt, sy, pout, pden);
    k4_final<<<32, 256, 0, stream>>>(pout, pden, (float*)d_out);
}